// Round 4
// baseline (820.797 us; speedup 1.0000x reference)
//
#include <hip/hip_runtime.h>
#include <stdint.h>

#define T_TOK 8192
#define HD    1024
#define ID    2816
#define NE    8
#define RCAP  17408   // 16384 pairs + up to 8*128 padding
#define NYT   (RCAP / 128)   // 136 row-tiles

typedef __bf16 bf16x8 __attribute__((ext_vector_type(8)));
typedef float  f32x4  __attribute__((ext_vector_type(4)));

__device__ __forceinline__ unsigned short f2bf(float f) {
  union { float f; unsigned u; } v; v.f = f;
  unsigned r = v.u + 0x7FFFu + ((v.u >> 16) & 1u);  // round-to-nearest-even
  return (unsigned short)(r >> 16);
}

__device__ __forceinline__ void gl16(const void* g, void* l) {
  __builtin_amdgcn_global_load_lds((__attribute__((address_space(1))) void*)g,
                                   (__attribute__((address_space(3))) void*)l,
                                   16, 0, 0);
}

// ---------------- K0: fused prep — weight transpose (blocks 0..16895) + router (16896..18943) ----------------
// Transpose: 4x4 register-block transpose, XOR slot swizzle in LDS (b64 ops, <=4-way).
// Router: 1 token/wave, fused x fp32->bf16 conversion (coalesced 128B/wave stores).
__global__ void k_prep(const float* __restrict__ x, const float* __restrict__ Wr,
                       const float* __restrict__ Wg, const float* __restrict__ Wu,
                       const float* __restrict__ Wd,
                       unsigned short* __restrict__ Wgt, unsigned short* __restrict__ Wut,
                       unsigned short* __restrict__ Wdt, unsigned short* __restrict__ xb,
                       int* __restrict__ cnt, float* __restrict__ psum,
                       int* __restrict__ tok_e, float* __restrict__ tok_w) {
  __shared__ __align__(16) unsigned short tl[64 * 64];  // transpose staging
  __shared__ float bp[NE];
  __shared__ int bc[NE];
  const int bid = blockIdx.x;
  const int t = threadIdx.x;

  if (bid < 16896) {
    // ---- transpose branch ----
    const int m = bid / 704, bx = bid - m * 704;
    const float* src; unsigned short* dst; int R, C;
    if (m < 8)       { src = Wg + (size_t)m * HD * ID;        dst = Wgt + (size_t)m * HD * ID;        R = HD; C = ID; }
    else if (m < 16) { src = Wu + (size_t)(m - 8) * HD * ID;  dst = Wut + (size_t)(m - 8) * HD * ID;  R = HD; C = ID; }
    else             { src = Wd + (size_t)(m - 16) * HD * ID; dst = Wdt + (size_t)(m - 16) * HD * ID; R = ID; C = HD; }
    const int tc = C / 64;
    const int tr = bx / tc, tcc = bx % tc;
    const int r0 = tr * 64, c0 = tcc * 64;
    const int rb = t >> 4;       // source row block 0..15
    const int c4 = t & 15;       // source col block 0..15
    const float* sp = src + (size_t)(r0 + rb * 4) * C + c0 + c4 * 4;
    float4 v[4];
#pragma unroll
    for (int i = 0; i < 4; ++i) v[i] = *(const float4*)(sp + (size_t)i * C);
    const float* vf = (const float*)v;
#pragma unroll
    for (int q = 0; q < 4; ++q) {
      const int c = c4 * 4 + q;                 // dst row
      ushort4 o;
      o.x = f2bf(vf[0 * 4 + q]); o.y = f2bf(vf[1 * 4 + q]);
      o.z = f2bf(vf[2 * 4 + q]); o.w = f2bf(vf[3 * 4 + q]);
      *(ushort4*)&tl[c * 64 + ((rb ^ (c & 15)) * 4)] = o;   // dst cols rb*4..rb*4+3
    }
    __syncthreads();
    const int orow = t >> 2, seg = t & 3;
    __align__(16) unsigned short tmp[16];
#pragma unroll
    for (int mI = 0; mI < 4; ++mI) {
      const int s = seg * 4 + mI;
      *(ushort4*)&tmp[mI * 4] = *(const ushort4*)&tl[orow * 64 + ((s ^ (orow & 15)) * 4)];
    }
    unsigned short* dp = dst + (size_t)(c0 + orow) * R + r0 + seg * 16;
    ((uint4*)dp)[0] = ((const uint4*)tmp)[0];
    ((uint4*)dp)[1] = ((const uint4*)tmp)[1];
  } else {
    // ---- router branch ----
    const int b = bid - 16896;
    if (t < NE) { bp[t] = 0.f; bc[t] = 0; }
    __syncthreads();
    const int lane = t & 63, w = t >> 6;
    const int tok = b * 4 + w;
    float acc[NE] = {0.f, 0.f, 0.f, 0.f, 0.f, 0.f, 0.f, 0.f};
    for (int h = lane; h < HD; h += 64) {
      const float xv = x[(size_t)tok * HD + h];
      xb[(size_t)tok * HD + h] = f2bf(xv);       // fused conversion
      const float4 w0 = *(const float4*)(Wr + h * 8);
      const float4 w1 = *(const float4*)(Wr + h * 8 + 4);
      acc[0] += xv * w0.x; acc[1] += xv * w0.y; acc[2] += xv * w0.z; acc[3] += xv * w0.w;
      acc[4] += xv * w1.x; acc[5] += xv * w1.y; acc[6] += xv * w1.z; acc[7] += xv * w1.w;
    }
#pragma unroll
    for (int e = 0; e < NE; ++e)
      for (int off = 32; off > 0; off >>= 1)
        acc[e] += __shfl_xor(acc[e], off, 64);
    if (lane == 0) {
      float mx = acc[0];
      for (int e = 1; e < NE; ++e) mx = fmaxf(mx, acc[e]);
      float p[NE], s = 0.f;
      for (int e = 0; e < NE; ++e) { p[e] = __expf(acc[e] - mx); s += p[e]; }
      const float inv = 1.f / s;
      for (int e = 0; e < NE; ++e) p[e] *= inv;
      int e0 = 0;
      for (int e = 1; e < NE; ++e) if (p[e] > p[e0]) e0 = e;
      int e1 = (e0 == 0) ? 1 : 0;
      for (int e = 0; e < NE; ++e) if (e != e0 && p[e] > p[e1]) e1 = e;
      const float v0 = p[e0], v1 = p[e1];
      const float invs = 1.f / (v0 + v1 + 1e-9f);
      tok_e[2 * tok] = e0;          tok_e[2 * tok + 1] = e1;
      tok_w[2 * tok] = v0 * invs;   tok_w[2 * tok + 1] = v1 * invs;
      atomicAdd(&bc[e0], 1); atomicAdd(&bc[e1], 1);
      for (int e = 0; e < NE; ++e) atomicAdd(&bp[e], p[e]);
    }
    __syncthreads();
    if (t < NE) { atomicAdd(&cnt[t], bc[t]); atomicAdd(&psum[t], bp[t]); }
  }
}

// ---------------- K2: offsets + aux loss + pad sentinels ----------------
__global__ void k_offsets(const int* __restrict__ cnt, const float* __restrict__ psum,
                          int* __restrict__ offp, int* __restrict__ pair_tok,
                          float* __restrict__ pair_w, float* __restrict__ loss_out) {
  __shared__ int soff[NE + 1], scnt[NE];
  if (threadIdx.x == 0) {
    int o = 0;
    for (int e = 0; e < NE; ++e) {
      soff[e] = o; scnt[e] = cnt[e];
      o += (scnt[e] + 127) & ~127;
    }
    soff[NE] = o;
    for (int e = 0; e <= NE; ++e) offp[e] = soff[e];
    float loss = 0.f;
    for (int e = 0; e < NE; ++e) loss += psum[e] * (float)scnt[e];
    loss *= (float)NE * 0.01f / ((float)T_TOK * (float)T_TOK);
    *loss_out = loss;
  }
  __syncthreads();
  for (int e = 0; e < NE; ++e) {
    const int base = soff[e] + scnt[e];
    const int n = soff[e + 1] - base;
    for (int j = threadIdx.x; j < n; j += blockDim.x) {
      pair_tok[base + j] = -1;
      pair_w[base + j] = 0.f;
    }
  }
}

// ---------------- K3: compaction (+ inverse map) ----------------
__global__ void k_scatter(const int* __restrict__ tok_e, const float* __restrict__ tok_w,
                          const int* __restrict__ offp, int* __restrict__ cursor,
                          int* __restrict__ pair_tok, float* __restrict__ pair_w,
                          int* __restrict__ inv_p) {
  const int t = blockIdx.x * 256 + threadIdx.x;
#pragma unroll
  for (int k = 0; k < 2; ++k) {
    const int e = tok_e[2 * t + k];
    const int pos = atomicAdd(&cursor[e], 1);
    const int idx = offp[e] + pos;
    pair_tok[idx] = t;
    pair_w[idx] = tok_w[2 * t + k];
    inv_p[2 * t + k] = idx;
  }
}

// ---------------- K4: stage1 fused gate+up GEMM + SwiGLU ----------------
// Grid: 1D, i-tile-major (consecutive blocks share the weight panel -> L2/L3 reuse;
// xb is 16.7MB, fully L3-resident, so re-reading it per i-tile group is cheap).
__launch_bounds__(256, 2)
__global__ void k_stage1(const unsigned short* __restrict__ xb,
                         const unsigned short* __restrict__ Wgt,
                         const unsigned short* __restrict__ Wut,
                         const int* __restrict__ offp,
                         const int* __restrict__ pair_tok,
                         unsigned short* __restrict__ act) {
  __shared__ __align__(16) unsigned short lA[8192];
  __shared__ __align__(16) unsigned short lBg[8192];
  __shared__ __align__(16) unsigned short lBu[8192];
  __shared__ int toks[128];

  const int wg = blockIdx.x;
  const int ytile = wg % NYT;
  const int i0 = (wg / NYT) * 128;
  const int row0 = ytile * 128;
  if (row0 >= offp[8]) return;
  int e = 0;
  while (offp[e + 1] <= row0) ++e;
  const int tid = threadIdx.x;
  if (tid < 128) {
    const int tk = pair_tok[row0 + tid];
    toks[tid] = tk < 0 ? 0 : tk;
  }
  __syncthreads();

  const int lane = tid & 63, w = tid >> 6;
  const unsigned short* gA[4];
  const unsigned short* gBg[4];
  const unsigned short* gBu[4];
  unsigned ldso[4];
  const unsigned short* wgtE = Wgt + (size_t)e * ID * HD;
  const unsigned short* wutE = Wut + (size_t)e * ID * HD;
#pragma unroll
  for (int j = 0; j < 4; ++j) {
    const int row = (w * 4 + j) * 8 + (lane >> 3);
    const int kb = (lane & 7) ^ (row & 7);
    gA[j]  = xb + (size_t)toks[row] * HD + kb * 8;
    gBg[j] = wgtE + (size_t)(i0 + row) * HD + kb * 8;
    gBu[j] = wutE + (size_t)(i0 + row) * HD + kb * 8;
    ldso[j] = (unsigned)(w * 4 + j) * 512u;
  }

  const f32x4 zero = {0.f, 0.f, 0.f, 0.f};
  f32x4 accg[4][4], accu[4][4];
#pragma unroll
  for (int a = 0; a < 4; ++a)
#pragma unroll
    for (int b = 0; b < 4; ++b) { accg[a][b] = zero; accu[a][b] = zero; }

  const int wm = (w & 1) * 64, wn = (w >> 1) * 64;
  const int colm = lane & 15, quad = lane >> 4;

  for (int kt = 0; kt < HD / 64; ++kt) {
    __syncthreads();
    const int ko = kt * 64;
#pragma unroll
    for (int j = 0; j < 4; ++j) {
      gl16(gA[j] + ko,  &lA[ldso[j]]);
      gl16(gBg[j] + ko, &lBg[ldso[j]]);
      gl16(gBu[j] + ko, &lBu[ldso[j]]);
    }
    __syncthreads();
#pragma unroll
    for (int kk = 0; kk < 2; ++kk) {
      const int kbl = kk * 4 + quad;
      bf16x8 af[4], bg[4], bu[4];
#pragma unroll
      for (int mf = 0; mf < 4; ++mf) {
        const int r = wm + mf * 16 + colm;
        af[mf] = *(const bf16x8*)&lA[r * 64 + ((kbl ^ (r & 7)) * 8)];
      }
#pragma unroll
      for (int nf = 0; nf < 4; ++nf) {
        const int r = wn + nf * 16 + colm;
        const int o = r * 64 + ((kbl ^ (r & 7)) * 8);
        bg[nf] = *(const bf16x8*)&lBg[o];
        bu[nf] = *(const bf16x8*)&lBu[o];
      }
#pragma unroll
      for (int mf = 0; mf < 4; ++mf)
#pragma unroll
        for (int nf = 0; nf < 4; ++nf) {
          accg[mf][nf] = __builtin_amdgcn_mfma_f32_16x16x32_bf16(af[mf], bg[nf], accg[mf][nf], 0, 0, 0);
          accu[mf][nf] = __builtin_amdgcn_mfma_f32_16x16x32_bf16(af[mf], bu[nf], accu[mf][nf], 0, 0, 0);
        }
    }
  }

#pragma unroll
  for (int mf = 0; mf < 4; ++mf) {
#pragma unroll
    for (int r = 0; r < 4; ++r) {
      const int orow = row0 + wm + mf * 16 + quad * 4 + r;
      unsigned short* arow = act + (size_t)orow * ID + i0 + wn + colm;
#pragma unroll
      for (int nf = 0; nf < 4; ++nf) {
        const float g = accg[mf][nf][r];
        const float u = accu[mf][nf][r];
        const float h = (g / (1.f + __expf(-g))) * u;
        arow[nf * 16] = f2bf(h);
      }
    }
  }
}

// ---------------- K5: stage2 down GEMM (contrib path, unconditional) ----------------
// contrib aliases the Wgt/Wut workspace region (dead after stage1; stream order
// guarantees stage1 completed). Grid: 1D, h-tile-major for Wdt panel reuse.
__launch_bounds__(256, 2)
__global__ void k_stage2(const unsigned short* __restrict__ act,
                         const unsigned short* __restrict__ Wdt,
                         const int* __restrict__ offp,
                         float* __restrict__ contrib) {   // [RCAP][HD]
  __shared__ __align__(16) unsigned short lA[8192];
  __shared__ __align__(16) unsigned short lB[8192];

  const int wg = blockIdx.x;
  const int ytile = wg % NYT;
  const int h0 = (wg / NYT) * 128;
  const int row0 = ytile * 128;
  if (row0 >= offp[8]) return;
  int e = 0;
  while (offp[e + 1] <= row0) ++e;
  const int tid = threadIdx.x;
  const int lane = tid & 63, w = tid >> 6;
  const unsigned short* gA[4];
  const unsigned short* gB[4];
  unsigned ldso[4];
  const unsigned short* wdE = Wdt + (size_t)e * HD * ID;
#pragma unroll
  for (int j = 0; j < 4; ++j) {
    const int row = (w * 4 + j) * 8 + (lane >> 3);
    const int kb = (lane & 7) ^ (row & 7);
    gA[j] = act + (size_t)(row0 + row) * ID + kb * 8;
    gB[j] = wdE + (size_t)(h0 + row) * ID + kb * 8;
    ldso[j] = (unsigned)(w * 4 + j) * 512u;
  }

  const f32x4 zero = {0.f, 0.f, 0.f, 0.f};
  f32x4 acc[4][4];
#pragma unroll
  for (int a = 0; a < 4; ++a)
#pragma unroll
    for (int b = 0; b < 4; ++b) acc[a][b] = zero;

  const int wm = (w & 1) * 64, wn = (w >> 1) * 64;
  const int colm = lane & 15, quad = lane >> 4;

  for (int kt = 0; kt < ID / 64; ++kt) {
    __syncthreads();
    const int ko = kt * 64;
#pragma unroll
    for (int j = 0; j < 4; ++j) {
      gl16(gA[j] + ko, &lA[ldso[j]]);
      gl16(gB[j] + ko, &lB[ldso[j]]);
    }
    __syncthreads();
#pragma unroll
    for (int kk = 0; kk < 2; ++kk) {
      const int kbl = kk * 4 + quad;
      bf16x8 af[4], bf_[4];
#pragma unroll
      for (int mf = 0; mf < 4; ++mf) {
        const int r = wm + mf * 16 + colm;
        af[mf] = *(const bf16x8*)&lA[r * 64 + ((kbl ^ (r & 7)) * 8)];
      }
#pragma unroll
      for (int nf = 0; nf < 4; ++nf) {
        const int r = wn + nf * 16 + colm;
        bf_[nf] = *(const bf16x8*)&lB[r * 64 + ((kbl ^ (r & 7)) * 8)];
      }
#pragma unroll
      for (int mf = 0; mf < 4; ++mf)
#pragma unroll
        for (int nf = 0; nf < 4; ++nf)
          acc[mf][nf] = __builtin_amdgcn_mfma_f32_16x16x32_bf16(af[mf], bf_[nf], acc[mf][nf], 0, 0, 0);
    }
  }

#pragma unroll
  for (int mf = 0; mf < 4; ++mf) {
#pragma unroll
    for (int r = 0; r < 4; ++r) {
      const int lrow = wm + mf * 16 + quad * 4 + r;
      float* crow = contrib + (size_t)(row0 + lrow) * HD + h0 + wn + colm;
#pragma unroll
      for (int nf = 0; nf < 4; ++nf)
        crow[nf * 16] = acc[mf][nf][r];
    }
  }
}

// ---------------- K6: combine (contrib path) ----------------
__global__ void k_combine(const float* __restrict__ contrib, const int* __restrict__ inv_p,
                          const float* __restrict__ tok_w, float* __restrict__ out) {
  const int t = blockIdx.x;
  const int h4 = threadIdx.x;
  const int p0 = inv_p[2 * t], p1 = inv_p[2 * t + 1];
  const float w0 = tok_w[2 * t], w1 = tok_w[2 * t + 1];
  const float4 a = ((const float4*)(contrib + (size_t)p0 * HD))[h4];
  const float4 b = ((const float4*)(contrib + (size_t)p1 * HD))[h4];
  float4 o;
  o.x = w0 * a.x + w1 * b.x;
  o.y = w0 * a.y + w1 * b.y;
  o.z = w0 * a.z + w1 * b.z;
  o.w = w0 * a.w + w1 * b.w;
  ((float4*)(out + (size_t)t * HD))[h4] = o;
}

extern "C" void kernel_launch(void* const* d_in, const int* in_sizes, int n_in,
                              void* d_out, int out_size, void* d_ws, size_t ws_size,
                              hipStream_t stream) {
  const float* x  = (const float*)d_in[0];
  const float* Wr = (const float*)d_in[1];
  const float* Wg = (const float*)d_in[2];
  const float* Wu = (const float*)d_in[3];
  const float* Wd = (const float*)d_in[4];
  float* out = (float*)d_out;

  char* ws = (char*)d_ws;
  const size_t off_xb  = 256;
  const size_t sz_xb   = (size_t)T_TOK * HD * 2;
  const size_t sz_w    = (size_t)NE * HD * ID * 2;
  const size_t off_wgt = off_xb + sz_xb;
  const size_t off_wut = off_wgt + sz_w;
  const size_t off_wdt = off_wut + sz_w;
  const size_t off_act = off_wdt + sz_w;
  const size_t sz_act  = (size_t)RCAP * ID * 2;
  const size_t off_ptk = off_act + sz_act;
  const size_t off_pw  = off_ptk + (size_t)RCAP * 4;
  const size_t off_te  = off_pw + (size_t)RCAP * 4;
  const size_t off_tw  = off_te + (size_t)T_TOK * 2 * 4;
  const size_t off_ip  = off_tw + (size_t)T_TOK * 2 * 4;
  const size_t need    = off_ip + (size_t)T_TOK * 2 * 4;
  if (ws_size < need) return;

  int*   cnt    = (int*)(ws + 0);
  float* psum   = (float*)(ws + 32);
  int*   cursor = (int*)(ws + 64);
  int*   offp   = (int*)(ws + 96);
  unsigned short* xb  = (unsigned short*)(ws + off_xb);
  unsigned short* Wgt = (unsigned short*)(ws + off_wgt);
  unsigned short* Wut = (unsigned short*)(ws + off_wut);
  unsigned short* Wdt = (unsigned short*)(ws + off_wdt);
  unsigned short* act = (unsigned short*)(ws + off_act);
  int*   pair_tok = (int*)(ws + off_ptk);
  float* pair_w   = (float*)(ws + off_pw);
  int*   tok_e    = (int*)(ws + off_te);
  float* tok_w    = (float*)(ws + off_tw);
  int*   inv_p    = (int*)(ws + off_ip);
  // contrib (RCAP*HD*4 = 71.3 MB) aliases Wgt+Wut (92.3 MB): dead after stage1.
  float* contrib  = (float*)(ws + off_wgt);

  hipMemsetAsync(ws, 0, 256, stream);

  k_prep<<<16896 + T_TOK / 4, 256, 0, stream>>>(x, Wr, Wg, Wu, Wd, Wgt, Wut, Wdt, xb,
                                                cnt, psum, tok_e, tok_w);
  k_offsets<<<1, 256, 0, stream>>>(cnt, psum, offp, pair_tok, pair_w, out + (size_t)T_TOK * HD);
  k_scatter<<<T_TOK / 256, 256, 0, stream>>>(tok_e, tok_w, offp, cursor, pair_tok, pair_w, inv_p);
  k_stage1<<<(ID / 128) * NYT, 256, 0, stream>>>(xb, Wgt, Wut, offp, pair_tok, act);
  k_stage2<<<(HD / 128) * NYT, 256, 0, stream>>>(act, Wdt, offp, contrib);
  k_combine<<<T_TOK, 256, 0, stream>>>(contrib, inv_p, tok_w, out);
}

// Round 5
// 791.084 us; speedup vs baseline: 1.0376x; 1.0376x over previous
//
#include <hip/hip_runtime.h>
#include <stdint.h>

#define T_TOK 8192
#define HD    1024
#define ID    2816
#define NE    8
#define RCAP  17408   // 16384 pairs + up to 8*128 padding
#define NYT   (RCAP / 128)   // 136 row-tiles

typedef __bf16 bf16x8 __attribute__((ext_vector_type(8)));
typedef float  f32x4  __attribute__((ext_vector_type(4)));

__device__ __forceinline__ unsigned short f2bf(float f) {
  union { float f; unsigned u; } v; v.f = f;
  unsigned r = v.u + 0x7FFFu + ((v.u >> 16) & 1u);  // round-to-nearest-even
  return (unsigned short)(r >> 16);
}

__device__ __forceinline__ void gl16(const void* g, void* l) {
  __builtin_amdgcn_global_load_lds((__attribute__((address_space(1))) void*)g,
                                   (__attribute__((address_space(3))) void*)l,
                                   16, 0, 0);
}

// inline-asm ds_read_b128: invisible to the compiler's memory legalizer, so it
// does NOT trigger the conservative `s_waitcnt vmcnt(0)` that a C++ LDS read
// after global_load_lds provokes (the round-1/2 pipeline killer). Ordering is
// handled manually: lgkmcnt(0) + sched_barrier(0) before the MFMA cluster.
__device__ __forceinline__ bf16x8 dsr128(unsigned a) {
  bf16x8 r;
  asm volatile("ds_read_b128 %0, %1" : "=v"(r) : "v"(a));
  return r;
}

#define S2VM(n) asm volatile("s_waitcnt vmcnt(" #n ")")
#define S2LG0   asm volatile("s_waitcnt lgkmcnt(0)")
#define SBAR0   __builtin_amdgcn_sched_barrier(0)
#define HBAR    __builtin_amdgcn_s_barrier()

// ---------------- K0: fused prep — weight transpose (blocks 0..16895) + router ----------------
__global__ void k_prep(const float* __restrict__ x, const float* __restrict__ Wr,
                       const float* __restrict__ Wg, const float* __restrict__ Wu,
                       const float* __restrict__ Wd,
                       unsigned short* __restrict__ Wgt, unsigned short* __restrict__ Wut,
                       unsigned short* __restrict__ Wdt, unsigned short* __restrict__ xb,
                       int* __restrict__ cnt, float* __restrict__ psum,
                       int* __restrict__ tok_e, float* __restrict__ tok_w) {
  __shared__ __align__(16) unsigned short tl[64 * 64];
  __shared__ float bp[NE];
  __shared__ int bc[NE];
  const int bid = blockIdx.x;
  const int t = threadIdx.x;

  if (bid < 16896) {
    const int m = bid / 704, bx = bid - m * 704;
    const float* src; unsigned short* dst; int R, C;
    if (m < 8)       { src = Wg + (size_t)m * HD * ID;        dst = Wgt + (size_t)m * HD * ID;        R = HD; C = ID; }
    else if (m < 16) { src = Wu + (size_t)(m - 8) * HD * ID;  dst = Wut + (size_t)(m - 8) * HD * ID;  R = HD; C = ID; }
    else             { src = Wd + (size_t)(m - 16) * HD * ID; dst = Wdt + (size_t)(m - 16) * HD * ID; R = ID; C = HD; }
    const int tc = C / 64;
    const int tr = bx / tc, tcc = bx % tc;
    const int r0 = tr * 64, c0 = tcc * 64;
    const int rb = t >> 4;
    const int c4 = t & 15;
    const float* sp = src + (size_t)(r0 + rb * 4) * C + c0 + c4 * 4;
    float4 v[4];
#pragma unroll
    for (int i = 0; i < 4; ++i) v[i] = *(const float4*)(sp + (size_t)i * C);
    const float* vf = (const float*)v;
#pragma unroll
    for (int q = 0; q < 4; ++q) {
      const int c = c4 * 4 + q;
      ushort4 o;
      o.x = f2bf(vf[0 * 4 + q]); o.y = f2bf(vf[1 * 4 + q]);
      o.z = f2bf(vf[2 * 4 + q]); o.w = f2bf(vf[3 * 4 + q]);
      *(ushort4*)&tl[c * 64 + ((rb ^ (c & 15)) * 4)] = o;
    }
    __syncthreads();
    const int orow = t >> 2, seg = t & 3;
    __align__(16) unsigned short tmp[16];
#pragma unroll
    for (int mI = 0; mI < 4; ++mI) {
      const int s = seg * 4 + mI;
      *(ushort4*)&tmp[mI * 4] = *(const ushort4*)&tl[orow * 64 + ((s ^ (orow & 15)) * 4)];
    }
    unsigned short* dp = dst + (size_t)(c0 + orow) * R + r0 + seg * 16;
    ((uint4*)dp)[0] = ((const uint4*)tmp)[0];
    ((uint4*)dp)[1] = ((const uint4*)tmp)[1];
  } else {
    const int b = bid - 16896;
    if (t < NE) { bp[t] = 0.f; bc[t] = 0; }
    __syncthreads();
    const int lane = t & 63, w = t >> 6;
    const int tok = b * 4 + w;
    float acc[NE] = {0.f, 0.f, 0.f, 0.f, 0.f, 0.f, 0.f, 0.f};
    for (int h = lane; h < HD; h += 64) {
      const float xv = x[(size_t)tok * HD + h];
      xb[(size_t)tok * HD + h] = f2bf(xv);
      const float4 w0 = *(const float4*)(Wr + h * 8);
      const float4 w1 = *(const float4*)(Wr + h * 8 + 4);
      acc[0] += xv * w0.x; acc[1] += xv * w0.y; acc[2] += xv * w0.z; acc[3] += xv * w0.w;
      acc[4] += xv * w1.x; acc[5] += xv * w1.y; acc[6] += xv * w1.z; acc[7] += xv * w1.w;
    }
#pragma unroll
    for (int e = 0; e < NE; ++e)
      for (int off = 32; off > 0; off >>= 1)
        acc[e] += __shfl_xor(acc[e], off, 64);
    if (lane == 0) {
      float mx = acc[0];
      for (int e = 1; e < NE; ++e) mx = fmaxf(mx, acc[e]);
      float p[NE], s = 0.f;
      for (int e = 0; e < NE; ++e) { p[e] = __expf(acc[e] - mx); s += p[e]; }
      const float inv = 1.f / s;
      for (int e = 0; e < NE; ++e) p[e] *= inv;
      int e0 = 0;
      for (int e = 1; e < NE; ++e) if (p[e] > p[e0]) e0 = e;
      int e1 = (e0 == 0) ? 1 : 0;
      for (int e = 0; e < NE; ++e) if (e != e0 && p[e] > p[e1]) e1 = e;
      const float v0 = p[e0], v1 = p[e1];
      const float invs = 1.f / (v0 + v1 + 1e-9f);
      tok_e[2 * tok] = e0;          tok_e[2 * tok + 1] = e1;
      tok_w[2 * tok] = v0 * invs;   tok_w[2 * tok + 1] = v1 * invs;
      atomicAdd(&bc[e0], 1); atomicAdd(&bc[e1], 1);
      for (int e = 0; e < NE; ++e) atomicAdd(&bp[e], p[e]);
    }
    __syncthreads();
    if (t < NE) { atomicAdd(&cnt[t], bc[t]); atomicAdd(&psum[t], bp[t]); }
  }
}

// ---------------- K2: offsets + aux loss + pad sentinels ----------------
__global__ void k_offsets(const int* __restrict__ cnt, const float* __restrict__ psum,
                          int* __restrict__ offp, int* __restrict__ pair_tok,
                          float* __restrict__ pair_w, float* __restrict__ loss_out) {
  __shared__ int soff[NE + 1], scnt[NE];
  if (threadIdx.x == 0) {
    int o = 0;
    for (int e = 0; e < NE; ++e) {
      soff[e] = o; scnt[e] = cnt[e];
      o += (scnt[e] + 127) & ~127;
    }
    soff[NE] = o;
    for (int e = 0; e <= NE; ++e) offp[e] = soff[e];
    float loss = 0.f;
    for (int e = 0; e < NE; ++e) loss += psum[e] * (float)scnt[e];
    loss *= (float)NE * 0.01f / ((float)T_TOK * (float)T_TOK);
    *loss_out = loss;
  }
  __syncthreads();
  for (int e = 0; e < NE; ++e) {
    const int base = soff[e] + scnt[e];
    const int n = soff[e + 1] - base;
    for (int j = threadIdx.x; j < n; j += blockDim.x) {
      pair_tok[base + j] = -1;
      pair_w[base + j] = 0.f;
    }
  }
}

// ---------------- K3: compaction (+ inverse map) ----------------
__global__ void k_scatter(const int* __restrict__ tok_e, const float* __restrict__ tok_w,
                          const int* __restrict__ offp, int* __restrict__ cursor,
                          int* __restrict__ pair_tok, float* __restrict__ pair_w,
                          int* __restrict__ inv_p) {
  const int t = blockIdx.x * 256 + threadIdx.x;
#pragma unroll
  for (int k = 0; k < 2; ++k) {
    const int e = tok_e[2 * t + k];
    const int pos = atomicAdd(&cursor[e], 1);
    const int idx = offp[e] + pos;
    pair_tok[idx] = t;
    pair_w[idx] = tok_w[2 * t + k];
    inv_p[2 * t + k] = idx;
  }
}

// ---------------- K4: stage1 fused gate+up GEMM + SwiGLU (proven m97 structure) ----------------
__launch_bounds__(256, 2)
__global__ void k_stage1(const unsigned short* __restrict__ xb,
                         const unsigned short* __restrict__ Wgt,
                         const unsigned short* __restrict__ Wut,
                         const int* __restrict__ offp,
                         const int* __restrict__ pair_tok,
                         unsigned short* __restrict__ act) {
  __shared__ __align__(16) unsigned short lA[8192];
  __shared__ __align__(16) unsigned short lBg[8192];
  __shared__ __align__(16) unsigned short lBu[8192];
  __shared__ int toks[128];

  const int row0 = blockIdx.y * 128;
  if (row0 >= offp[8]) return;
  int e = 0;
  while (offp[e + 1] <= row0) ++e;
  const int i0 = blockIdx.x * 128;
  const int tid = threadIdx.x;
  if (tid < 128) {
    const int tk = pair_tok[row0 + tid];
    toks[tid] = tk < 0 ? 0 : tk;
  }
  __syncthreads();

  const int lane = tid & 63, w = tid >> 6;
  const unsigned short* gA[4];
  const unsigned short* gBg[4];
  const unsigned short* gBu[4];
  unsigned ldso[4];
  const unsigned short* wgtE = Wgt + (size_t)e * ID * HD;
  const unsigned short* wutE = Wut + (size_t)e * ID * HD;
#pragma unroll
  for (int j = 0; j < 4; ++j) {
    const int row = (w * 4 + j) * 8 + (lane >> 3);
    const int kb = (lane & 7) ^ (row & 7);
    gA[j]  = xb + (size_t)toks[row] * HD + kb * 8;
    gBg[j] = wgtE + (size_t)(i0 + row) * HD + kb * 8;
    gBu[j] = wutE + (size_t)(i0 + row) * HD + kb * 8;
    ldso[j] = (unsigned)(w * 4 + j) * 512u;
  }

  const f32x4 zero = {0.f, 0.f, 0.f, 0.f};
  f32x4 accg[4][4], accu[4][4];
#pragma unroll
  for (int a = 0; a < 4; ++a)
#pragma unroll
    for (int b = 0; b < 4; ++b) { accg[a][b] = zero; accu[a][b] = zero; }

  const int wm = (w & 1) * 64, wn = (w >> 1) * 64;
  const int colm = lane & 15, quad = lane >> 4;

  for (int kt = 0; kt < HD / 64; ++kt) {
    __syncthreads();
    const int ko = kt * 64;
#pragma unroll
    for (int j = 0; j < 4; ++j) {
      gl16(gA[j] + ko,  &lA[ldso[j]]);
      gl16(gBg[j] + ko, &lBg[ldso[j]]);
      gl16(gBu[j] + ko, &lBu[ldso[j]]);
    }
    __syncthreads();
#pragma unroll
    for (int kk = 0; kk < 2; ++kk) {
      const int kbl = kk * 4 + quad;
      bf16x8 af[4], bg[4], bu[4];
#pragma unroll
      for (int mf = 0; mf < 4; ++mf) {
        const int r = wm + mf * 16 + colm;
        af[mf] = *(const bf16x8*)&lA[r * 64 + ((kbl ^ (r & 7)) * 8)];
      }
#pragma unroll
      for (int nf = 0; nf < 4; ++nf) {
        const int r = wn + nf * 16 + colm;
        const int o = r * 64 + ((kbl ^ (r & 7)) * 8);
        bg[nf] = *(const bf16x8*)&lBg[o];
        bu[nf] = *(const bf16x8*)&lBu[o];
      }
#pragma unroll
      for (int mf = 0; mf < 4; ++mf)
#pragma unroll
        for (int nf = 0; nf < 4; ++nf) {
          accg[mf][nf] = __builtin_amdgcn_mfma_f32_16x16x32_bf16(af[mf], bg[nf], accg[mf][nf], 0, 0, 0);
          accu[mf][nf] = __builtin_amdgcn_mfma_f32_16x16x32_bf16(af[mf], bu[nf], accu[mf][nf], 0, 0, 0);
        }
    }
  }

#pragma unroll
  for (int mf = 0; mf < 4; ++mf) {
#pragma unroll
    for (int r = 0; r < 4; ++r) {
      const int orow = row0 + wm + mf * 16 + quad * 4 + r;
      unsigned short* arow = act + (size_t)orow * ID + i0 + wn + colm;
#pragma unroll
      for (int nf = 0; nf < 4; ++nf) {
        const float g = accg[mf][nf][r];
        const float u = accu[mf][nf][r];
        const float h = (g / (1.f + __expf(-g))) * u;
        arow[nf * 16] = f2bf(h);
      }
    }
  }
}

// ---------------- K5: stage2 down GEMM — counted-vmcnt pipeline (asm ds_read) ----------------
// BM=128, BN=128, BK=64, 4 waves (2M x 2N, 64x64 each). 2 phases per K-tile (k-half h).
// LDS 64KB: A [buf][h][128][32] ushorts @0; B same @16384. Double-buffered; staging
// into sub-regions whose last reader was >=1 barrier ago; 4 gl16/thread/phase;
// vmcnt(8) = 2 phases in flight x 4 loads. Swizzle: slot = quad ^ ((row>>1)&3)
// (conflict-free, verified round 2); source pre-swizzled ks = (l&3)^((l>>3)&3).
#define STG2(b, h, t) do { \
  const int go_ = (t) * 64 + (h) * 32; \
  char* lb_ = (char*)smem + ((b) * 16384 + (h) * 8192) + wdst; \
  gl16(srcA0 + go_, lb_); \
  gl16(srcA1 + go_, lb_ + 4096); \
  gl16(srcB0 + go_, lb_ + 32768); \
  gl16(srcB1 + go_, lb_ + 32768 + 4096); \
} while (0)

#define S2_PHASE(b, h, STAGE, VMW) do { \
  bf16x8 af[4], bf_[4]; \
  _Pragma("unroll") for (int i_ = 0; i_ < 4; ++i_) \
    af[i_] = dsr128(aRd + (b) * 16384 + (h) * 8192 + i_ * 1024); \
  _Pragma("unroll") for (int i_ = 0; i_ < 4; ++i_) \
    bf_[i_] = dsr128(bRd + (b) * 16384 + (h) * 8192 + i_ * 1024); \
  STAGE; \
  SBAR0; HBAR; S2LG0; SBAR0; \
  __builtin_amdgcn_s_setprio(1); \
  _Pragma("unroll") for (int mf_ = 0; mf_ < 4; ++mf_) \
    _Pragma("unroll") for (int nf_ = 0; nf_ < 4; ++nf_) \
      acc[mf_][nf_] = __builtin_amdgcn_mfma_f32_16x16x32_bf16(af[mf_], bf_[nf_], acc[mf_][nf_], 0, 0, 0); \
  __builtin_amdgcn_s_setprio(0); \
  SBAR0; \
  VMW; \
  HBAR; \
} while (0)

__launch_bounds__(256, 2)
__global__ void k_stage2(const unsigned short* __restrict__ act,
                         const unsigned short* __restrict__ Wdt,
                         const int* __restrict__ offp,
                         float* __restrict__ contrib) {   // [RCAP][HD]
  __shared__ __align__(16) unsigned short smem[32768];    // 64 KiB

  // XCD-aware bijective swizzle: 1088 = 8 * 136; each XCD gets 17 row-panels x 8 h-tiles,
  // 8 consecutive blocks share a row-panel (A reuse in XCD L2).
  int wg = blockIdx.x;
  wg = (wg & 7) * 136 + (wg >> 3);
  const int htile = wg & 7, ytile = wg >> 3;
  const int row0 = ytile * 128;
  if (row0 >= offp[8]) return;
  int e = 0;
  while (offp[e + 1] <= row0) ++e;
  const int h0 = htile * 128;

  const int tid = threadIdx.x;
  const int l = tid & 63, w = tid >> 6;
  const int colm = l & 15, quad = l >> 4;
  const int wm = (w & 1) * 64, wn = (w >> 1) * 64;

  // staging: wave w covers rows w*16 + (l>>2) (+64 for the second round)
  const int rr = w * 16 + (l >> 2);
  const int ks = (l & 3) ^ ((l >> 3) & 3);
  const unsigned short* wdE = Wdt + (size_t)e * HD * ID;
  const unsigned short* srcA0 = act + (size_t)(row0 + rr) * ID + ks * 8;
  const unsigned short* srcA1 = act + (size_t)(row0 + 64 + rr) * ID + ks * 8;
  const unsigned short* srcB0 = wdE + (size_t)(h0 + rr) * ID + ks * 8;
  const unsigned short* srcB1 = wdE + (size_t)(h0 + 64 + rr) * ID + ks * 8;
  const int wdst = w * 1024;   // bytes; HW adds lane*16

  // asm ds_read byte addresses (AS(3) offset)
  const unsigned ldsBase =
      (unsigned)(uintptr_t)(__attribute__((address_space(3))) unsigned short*)smem;
  const int slotB = (quad ^ ((colm >> 1) & 3)) * 16;
  const unsigned aRd = ldsBase + (unsigned)((wm + colm) * 64 + slotB);
  const unsigned bRd = ldsBase + 32768u + (unsigned)((wn + colm) * 64 + slotB);

  const f32x4 zero = {0.f, 0.f, 0.f, 0.f};
  f32x4 acc[4][4];
#pragma unroll
  for (int a = 0; a < 4; ++a)
#pragma unroll
    for (int b = 0; b < 4; ++b) acc[a][b] = zero;

  // prologue: tile0 both halves + tile1 half0; wait tile0 (12 issued, keep <=4)
  STG2(0, 0, 0);
  STG2(0, 1, 0);
  STG2(1, 0, 1);
  S2VM(4); HBAR;

  for (int T = 0; T < 44; T += 2) {
    // tile T (buffer 0)
    S2_PHASE(0, 0,
      { if (T + 1 < 44) STG2(1, 1, T + 1); },
      { if (T + 1 < 44) { S2VM(8); } else { S2VM(0); } });
    S2_PHASE(0, 1,
      { if (T + 2 < 44) STG2(0, 0, T + 2); },
      { if (T + 2 < 44) { S2VM(8); } else if (T + 1 < 44) { S2VM(4); } else { S2VM(0); } });
    // tile T+1 (buffer 1)
    S2_PHASE(1, 0,
      { if (T + 2 < 44) STG2(0, 1, T + 2); },
      { if (T + 2 < 44) { S2VM(8); } else { S2VM(0); } });
    S2_PHASE(1, 1,
      { if (T + 3 < 44) STG2(1, 0, T + 3); },
      { if (T + 3 < 44) { S2VM(8); } else if (T + 2 < 44) { S2VM(4); } else { S2VM(0); } });
  }

#pragma unroll
  for (int mf = 0; mf < 4; ++mf) {
#pragma unroll
    for (int r = 0; r < 4; ++r) {
      const int lrow = wm + mf * 16 + quad * 4 + r;
      float* crow = contrib + (size_t)(row0 + lrow) * HD + h0 + wn + colm;
#pragma unroll
      for (int nf = 0; nf < 4; ++nf)
        crow[nf * 16] = acc[mf][nf][r];
    }
  }
}

// ---------------- K6: combine (contrib path) ----------------
__global__ void k_combine(const float* __restrict__ contrib, const int* __restrict__ inv_p,
                          const float* __restrict__ tok_w, float* __restrict__ out) {
  const int t = blockIdx.x;
  const int h4 = threadIdx.x;
  const int p0 = inv_p[2 * t], p1 = inv_p[2 * t + 1];
  const float w0 = tok_w[2 * t], w1 = tok_w[2 * t + 1];
  const float4 a = ((const float4*)(contrib + (size_t)p0 * HD))[h4];
  const float4 b = ((const float4*)(contrib + (size_t)p1 * HD))[h4];
  float4 o;
  o.x = w0 * a.x + w1 * b.x;
  o.y = w0 * a.y + w1 * b.y;
  o.z = w0 * a.z + w1 * b.z;
  o.w = w0 * a.w + w1 * b.w;
  ((float4*)(out + (size_t)t * HD))[h4] = o;
}

extern "C" void kernel_launch(void* const* d_in, const int* in_sizes, int n_in,
                              void* d_out, int out_size, void* d_ws, size_t ws_size,
                              hipStream_t stream) {
  const float* x  = (const float*)d_in[0];
  const float* Wr = (const float*)d_in[1];
  const float* Wg = (const float*)d_in[2];
  const float* Wu = (const float*)d_in[3];
  const float* Wd = (const float*)d_in[4];
  float* out = (float*)d_out;

  char* ws = (char*)d_ws;
  const size_t off_xb  = 256;
  const size_t sz_xb   = (size_t)T_TOK * HD * 2;
  const size_t sz_w    = (size_t)NE * HD * ID * 2;
  const size_t off_wgt = off_xb + sz_xb;
  const size_t off_wut = off_wgt + sz_w;
  const size_t off_wdt = off_wut + sz_w;
  const size_t off_act = off_wdt + sz_w;
  const size_t sz_act  = (size_t)RCAP * ID * 2;
  const size_t off_ptk = off_act + sz_act;
  const size_t off_pw  = off_ptk + (size_t)RCAP * 4;
  const size_t off_te  = off_pw + (size_t)RCAP * 4;
  const size_t off_tw  = off_te + (size_t)T_TOK * 2 * 4;
  const size_t off_ip  = off_tw + (size_t)T_TOK * 2 * 4;
  const size_t need    = off_ip + (size_t)T_TOK * 2 * 4;
  if (ws_size < need) return;

  int*   cnt    = (int*)(ws + 0);
  float* psum   = (float*)(ws + 32);
  int*   cursor = (int*)(ws + 64);
  int*   offp   = (int*)(ws + 96);
  unsigned short* xb  = (unsigned short*)(ws + off_xb);
  unsigned short* Wgt = (unsigned short*)(ws + off_wgt);
  unsigned short* Wut = (unsigned short*)(ws + off_wut);
  unsigned short* Wdt = (unsigned short*)(ws + off_wdt);
  unsigned short* act = (unsigned short*)(ws + off_act);
  int*   pair_tok = (int*)(ws + off_ptk);
  float* pair_w   = (float*)(ws + off_pw);
  int*   tok_e    = (int*)(ws + off_te);
  float* tok_w    = (float*)(ws + off_tw);
  int*   inv_p    = (int*)(ws + off_ip);
  // contrib (RCAP*HD*4 = 71.3 MB) aliases Wgt+Wut (92.3 MB): dead after stage1.
  float* contrib  = (float*)(ws + off_wgt);

  hipMemsetAsync(ws, 0, 256, stream);

  k_prep<<<16896 + T_TOK / 4, 256, 0, stream>>>(x, Wr, Wg, Wu, Wd, Wgt, Wut, Wdt, xb,
                                                cnt, psum, tok_e, tok_w);
  k_offsets<<<1, 256, 0, stream>>>(cnt, psum, offp, pair_tok, pair_w, out + (size_t)T_TOK * HD);
  k_scatter<<<T_TOK / 256, 256, 0, stream>>>(tok_e, tok_w, offp, cursor, pair_tok, pair_w, inv_p);
  k_stage1<<<dim3(ID / 128, NYT), 256, 0, stream>>>(xb, Wgt, Wut, offp, pair_tok, act);
  k_stage2<<<NYT * (HD / 128), 256, 0, stream>>>(act, Wdt, offp, contrib);
  k_combine<<<T_TOK, 256, 0, stream>>>(contrib, inv_p, tok_w, out);
}